// Round 3
// baseline (349.108 us; speedup 1.0000x reference)
//
#include <hip/hip_runtime.h>
#include <hip/hip_bf16.h>

// DCTBlur reference:  out = D (M .* (D x D^T)) D^T  with M = m m^T, m_k = exp(-(pi k/N)^2 t),
// t = sigma^2/2, sigma = blur_sigmas[fwd_steps[b]].
// => out = H x H^T  with  H = D diag(m) D   (NOT symmetric; per-step, 32 variants).
// Precompute H numerically (fp32) -> bf16.
// Main kernel (one block = one image x one 32-col output band, grid 3072):
//   Phase 1: Z[k][j] = sum_m X[k][m] * H[j0+j][m]   (Z = X H^T), Z^T -> LDS (16KB, swizzled)
//   Phase 2: out[i][j0+j] = sum_k H[i][k] * Z[k][j]
// Register budget is the whole game: acc[2][2] (16 AGPR) + frags keeps unified regs <=64
// -> 8 waves/SIMD -> 4 blocks/CU resident (vs 1 block/CU in round 2's acc[4][4] version).
// XCD-chunked task swizzle keeps all 8 bands of an image on one XCD's L2.

#define NN 256
#define NSTEP 32

typedef __attribute__((ext_vector_type(8))) __bf16 bf16x8;
typedef __attribute__((ext_vector_type(4))) __bf16 bf16x4;
typedef __attribute__((ext_vector_type(4))) float f32x4;
typedef __attribute__((ext_vector_type(8))) unsigned short u16x8;
typedef __attribute__((ext_vector_type(4))) unsigned short u16x4;

__device__ __align__(16) float g_D[NN][NN];
__device__ __align__(16) unsigned short g_H[NSTEP][NN][NN];

static __device__ inline unsigned short f2bfu(float x) {
  unsigned u = __builtin_bit_cast(unsigned, x);
  u += 0x7fffu + ((u >> 16) & 1u);   // round-to-nearest-even
  return (unsigned short)(u >> 16);
}

// ---------------- D matrix: 256 blocks x 256 threads ----------------
// D[k][n] = sqrt(2/N) * cos(pi*(n+0.5)*k/N), row 0 scaled by 1/sqrt(2).
// Phase reduced exactly in integers: angle = pi*q/512, q = k*(2n+1) mod 1024.
__global__ void compute_D() {
  int k = blockIdx.x;
  int n = threadIdx.x;
  int q = (k * (2 * n + 1)) & 1023;
  float c = cosf((float)q * (float)(M_PI / 512.0));
  float v = 0.08838834764831845f * c;              // sqrt(2/256)
  if (k == 0) v *= 0.70710678118654752f;
  g_D[k][n] = v;
}

// ---------------- H = D diag(m) D : 32*32 blocks x 256 threads ----------------
__global__ void compute_H(const float* __restrict__ sigmas) {
  __shared__ float a[8][NN];
  int s = blockIdx.x >> 5;
  int i0 = (blockIdx.x & 31) * 8;
  int j = threadIdx.x;

  float sg = sigmas[s];
  float t = 0.5f * sg * sg;
  float fk = (float)M_PI * (float)j * (1.0f / (float)NN);
  float m = expf(-fk * fk * t);
#pragma unroll
  for (int r = 0; r < 8; ++r) a[r][j] = g_D[i0 + r][j] * m;
  __syncthreads();

  float acc[8];
#pragma unroll
  for (int r = 0; r < 8; ++r) acc[r] = 0.f;
  for (int k = 0; k < NN; ++k) {
    float d = g_D[k][j];
#pragma unroll
    for (int r = 0; r < 8; ++r) acc[r] += a[r][k] * d;
  }
#pragma unroll
  for (int r = 0; r < 8; ++r) g_H[s][i0 + r][j] = f2bfu(acc[r]);
}

// ---------------- main fused kernel ----------------
// grid 3072 = 384 images x 8 col-bands of 32; block 512 threads = 8 waves.
// Wave w owns 32 k-rows (phase 1) / 32 i-rows (phase 2); whole block shares the 32-col band.
__global__ __launch_bounds__(512, 8) void dct_blur_main(
    const float* __restrict__ x, const int* __restrict__ steps,
    float* __restrict__ out) {
  __shared__ __align__(16) unsigned short Zt[32 * 256];  // [j][k] swizzled, 16 KB

  int bid = blockIdx.x;
  // XCD-chunked: XCD q gets tasks q*384..q*384+383 (48 consecutive images) -> image L2-local.
  int task = (bid & 7) * 384 + (bid >> 3);
  int img = task >> 3;      // 0..383
  int band = task & 7;      // 0..7
  int b = img / 3;
  int s = steps[b];

  const float* X = x + (size_t)img * (NN * NN);
  float* O = out + (size_t)img * (NN * NN);
  const unsigned short* H = &g_H[s][0][0];

  int tid = (int)threadIdx.x;
  int lane = tid & 63;
  int w = tid >> 6;       // 0..7
  int l16 = lane & 15;
  int hi = lane >> 4;     // 0..3
  int j0 = band * 32;
  int mrow0 = w * 32;     // wave's 32-row slice (k in phase 1, i in phase 2)

  // ================= Phase 1: Z = X H^T (this band's 32 cols) =================
  f32x4 acc[2][2];
#pragma unroll
  for (int mi = 0; mi < 2; ++mi)
#pragma unroll
    for (int ni = 0; ni < 2; ++ni)
      acc[mi][ni] = (f32x4){0.f, 0.f, 0.f, 0.f};

#pragma unroll 1
  for (int kk = 0; kk < 8; ++kk) {
    int m0 = kk * 32;
    bf16x8 a[2], bb[2];
#pragma unroll
    for (int ni = 0; ni < 2; ++ni) {
      int hrow = j0 + ni * 16 + l16;                // H row (= output col j)
      u16x8 g = *reinterpret_cast<const u16x8*>(H + hrow * NN + m0 + hi * 8);
      bb[ni] = __builtin_bit_cast(bf16x8, g);
    }
#pragma unroll
    for (int mi = 0; mi < 2; ++mi) {
      int row = mrow0 + mi * 16 + l16;              // X row (= Z k-index)
      const f32x4* p = reinterpret_cast<const f32x4*>(X + row * NN + m0 + hi * 8);
      f32x4 v0 = p[0], v1 = p[1];
      bf16x8 av;
#pragma unroll
      for (int e = 0; e < 4; ++e) { av[e] = (__bf16)v0[e]; av[4 + e] = (__bf16)v1[e]; }
      a[mi] = av;
    }
#pragma unroll
    for (int mi = 0; mi < 2; ++mi)
#pragma unroll
      for (int ni = 0; ni < 2; ++ni)
        acc[mi][ni] = __builtin_amdgcn_mfma_f32_16x16x32_bf16(a[mi], bb[ni], acc[mi][ni], 0, 0, 0);
  }

  // write Z^T to LDS: element (j, k) at ushort idx ((j<<8)+k) ^ ((j&7)<<3)
#pragma unroll
  for (int mi = 0; mi < 2; ++mi) {
#pragma unroll
    for (int ni = 0; ni < 2; ++ni) {
      int j = ni * 16 + l16;                        // 0..31 band-local col
      int kb = mrow0 + mi * 16 + 4 * hi;
      bf16x4 pk;
#pragma unroll
      for (int r = 0; r < 4; ++r) pk[r] = (__bf16)acc[mi][ni][r];
      int idx = ((j << 8) + kb) ^ ((j & 7) << 3);
      *reinterpret_cast<u16x4*>(&Zt[idx]) = __builtin_bit_cast(u16x4, pk);
    }
  }

  __syncthreads();

  // ================= Phase 2: out = H Z =================
  f32x4 acc2[2][2];
#pragma unroll
  for (int mi = 0; mi < 2; ++mi)
#pragma unroll
    for (int ni = 0; ni < 2; ++ni)
      acc2[mi][ni] = (f32x4){0.f, 0.f, 0.f, 0.f};

#pragma unroll 1
  for (int kk = 0; kk < 8; ++kk) {
    int k0 = kk * 32;
    bf16x8 a2[2], b2[2];
#pragma unroll
    for (int mi = 0; mi < 2; ++mi) {
      int irow = mrow0 + mi * 16 + l16;             // output row i
      u16x8 g = *reinterpret_cast<const u16x8*>(H + irow * NN + k0 + hi * 8);
      a2[mi] = __builtin_bit_cast(bf16x8, g);
    }
#pragma unroll
    for (int ni = 0; ni < 2; ++ni) {
      int jr = ni * 16 + l16;
      int idx = ((jr << 8) + k0 + hi * 8) ^ ((jr & 7) << 3);
      u16x8 z = *reinterpret_cast<const u16x8*>(&Zt[idx]);
      b2[ni] = __builtin_bit_cast(bf16x8, z);
    }
#pragma unroll
    for (int mi = 0; mi < 2; ++mi)
#pragma unroll
      for (int ni = 0; ni < 2; ++ni)
        acc2[mi][ni] = __builtin_amdgcn_mfma_f32_16x16x32_bf16(a2[mi], b2[ni], acc2[mi][ni], 0, 0, 0);
  }

  // epilogue: fp32 store
#pragma unroll
  for (int mi = 0; mi < 2; ++mi) {
#pragma unroll
    for (int ni = 0; ni < 2; ++ni) {
      int ibase = mrow0 + mi * 16 + 4 * hi;
      int jg = j0 + ni * 16 + l16;
#pragma unroll
      for (int r = 0; r < 4; ++r)
        O[(ibase + r) * NN + jg] = acc2[mi][ni][r];
    }
  }
}

extern "C" void kernel_launch(void* const* d_in, const int* in_sizes, int n_in,
                              void* d_out, int out_size, void* d_ws, size_t ws_size,
                              hipStream_t stream) {
  (void)in_sizes; (void)n_in; (void)out_size; (void)d_ws; (void)ws_size;
  const float* x = (const float*)d_in[0];
  const float* sigmas = (const float*)d_in[1];
  const int* steps = (const int*)d_in[2];
  float* out = (float*)d_out;

  compute_D<<<dim3(NN), dim3(NN), 0, stream>>>();
  compute_H<<<dim3(NSTEP * 32), dim3(NN), 0, stream>>>(sigmas);
  dct_blur_main<<<dim3(3072), dim3(512), 0, stream>>>(x, steps, out);
}

// Round 5
// 332.255 us; speedup vs baseline: 1.0507x; 1.0507x over previous
//
#include <hip/hip_runtime.h>
#include <hip/hip_bf16.h>
#include <math.h>

// DCTBlur:  out = H x H^T,  H = D diag(m) D,  m_k = exp(-(pi k/N)^2 t), t = sigma^2/2.
// Analytic H:  H[i][j] = a_i/N [ cos(phi_i)(Uc[p1]+Uc[p2]) - sin(phi_i)(Us[p1]+Us[p2]) ]
//   p1 = 2(i-j)-1, p2 = 2(i+j)+1 (mod 4N, always odd), phi_i = pi*i/(2N),
//   Uc[p] = sum_k m_k a_k cos(pi k p/(2N)),  Us likewise with sin,  a_0 = 1/sqrt(2) else 1.
// Pass 1: PT[b][j][r] = sum_m X[r][m] H[j][m]   ((X H^T)^T, bf16 scratch, 50 MB)
// Pass 2: out[i][j]   = sum_k H[i][k] PT[j][k]
// Both passes: barrier-free streaming MFMA GEMMs, 64x64 wave tiles (acc[4][4]),
// 256-thr blocks (2x2 waves), A/B fragments contiguous along K directly from global.

#define NN 256
#define NSTEP 32
#define NIMG 384

typedef __attribute__((ext_vector_type(8))) __bf16 bf16x8;
typedef __attribute__((ext_vector_type(4))) __bf16 bf16x4;
typedef __attribute__((ext_vector_type(4))) float f32x4;
typedef __attribute__((ext_vector_type(8))) unsigned short u16x8;
typedef __attribute__((ext_vector_type(4))) unsigned short u16x4;

__device__ __align__(16) float g_Uc[NSTEP][512];
__device__ __align__(16) float g_Us[NSTEP][512];
__device__ __align__(16) unsigned short g_H[NSTEP][NN][NN];
__device__ __align__(16) unsigned short g_PT[NIMG * NN * NN];  // 50.3 MB bf16 scratch

static __device__ inline unsigned short f2bfu(float x) {
  unsigned u = __builtin_bit_cast(unsigned, x);
  u += 0x7fffu + ((u >> 16) & 1u);   // round-to-nearest-even
  return (unsigned short)(u >> 16);
}

// ---------------- U tables: 256 blocks x 64 threads ----------------
// block = (step s, 64-entry chunk); thread owns odd p = 2q+1.
__global__ void compute_U(const float* __restrict__ sigmas) {
  int s = blockIdx.x >> 3;
  int q = ((blockIdx.x & 7) << 6) + threadIdx.x;   // 0..511
  int p = 2 * q + 1;
  float sg = sigmas[s];
  float t = 0.5f * sg * sg;
  float c = (float)(M_PI / 256.0) * (float)(M_PI / 256.0) * t;
  // m_k = exp(-c k^2) via multiplicative recurrence
  float m = __expf(-c);           // m_1
  float ratio = __expf(-3.0f * c);
  float qf = __expf(-2.0f * c);
  float sumc = 0.70710678118654752f;  // k=0: a_0 * cos(0)
  float sums = 0.0f;
  for (int k = 1; k < NN; ++k) {
    int ph = (k * p) & 1023;
    float ang = (float)ph * (float)(M_PI / 512.0);
    float sn, cs;
    sincosf(ang, &sn, &cs);
    sumc += m * cs;
    sums += m * sn;
    m *= ratio;
    ratio *= qf;
  }
  g_Uc[s][q] = sumc;
  g_Us[s][q] = sums;
}

// ---------------- H assembly: 8192 blocks x 256 threads ----------------
__global__ void compute_H(const float* __restrict__ sigmas) {
  int s = blockIdx.x >> 8;
  int i = blockIdx.x & 255;
  int j = threadIdx.x;
  int q1 = ((2 * (i - j) - 1) & 1023) >> 1;
  int q2 = ((2 * (i + j) + 1) & 1023) >> 1;
  float phi = (float)i * (float)(M_PI / 512.0);
  float sp, cp;
  sincosf(phi, &sp, &cp);
  float v = (g_Uc[s][q1] + g_Uc[s][q2]) * cp - (g_Us[s][q1] + g_Us[s][q2]) * sp;
  v *= (1.0f / (float)NN);
  if (i == 0) v *= 0.70710678118654752f;
  g_H[s][i][j] = f2bfu(v);
}

// ---------------- pass 1: PT = (X H^T)^T ----------------
// grid 1536 = 384 img x 4 quads; 256 thr = 4 waves (2x2 of 64x64).
__global__ __launch_bounds__(256, 3) void dct_pass1(
    const float* __restrict__ x, const int* __restrict__ steps) {
  int bid = blockIdx.x;
  int task = (bid & 7) * 192 + (bid >> 3);   // XCD-chunked: same img -> same XCD
  int img = task >> 2;
  int quad = task & 3;
  int s = steps[img / 3];

  const float* X = x + (size_t)img * (NN * NN);
  const unsigned short* H = &g_H[s][0][0];
  unsigned short* PT = g_PT + (size_t)img * (NN * NN);

  int tid = (int)threadIdx.x;
  int lane = tid & 63;
  int w = tid >> 6;
  int l16 = lane & 15;
  int hi = lane >> 4;
  int mrow0 = (quad >> 1) * 128 + (w >> 1) * 64;   // X row band (r)
  int ncol0 = (quad & 1) * 128 + (w & 1) * 64;     // output col band (j = H row)

  f32x4 acc[4][4];
#pragma unroll
  for (int mi = 0; mi < 4; ++mi)
#pragma unroll
    for (int ni = 0; ni < 4; ++ni)
      acc[mi][ni] = (f32x4){0.f, 0.f, 0.f, 0.f};

#pragma unroll 2
  for (int kk = 0; kk < 8; ++kk) {
    int m0 = kk * 32;
    bf16x8 a[4], bb[4];
#pragma unroll
    for (int ni = 0; ni < 4; ++ni) {
      int hrow = ncol0 + ni * 16 + l16;
      u16x8 g = *reinterpret_cast<const u16x8*>(H + hrow * NN + m0 + hi * 8);
      bb[ni] = __builtin_bit_cast(bf16x8, g);
    }
#pragma unroll
    for (int mi = 0; mi < 4; ++mi) {
      int row = mrow0 + mi * 16 + l16;
      const f32x4* p = reinterpret_cast<const f32x4*>(X + row * NN + m0 + hi * 8);
      f32x4 v0 = p[0], v1 = p[1];
      bf16x8 av;
#pragma unroll
      for (int e = 0; e < 4; ++e) { av[e] = (__bf16)v0[e]; av[4 + e] = (__bf16)v1[e]; }
      a[mi] = av;
    }
#pragma unroll
    for (int mi = 0; mi < 4; ++mi)
#pragma unroll
      for (int ni = 0; ni < 4; ++ni)
        acc[mi][ni] = __builtin_amdgcn_mfma_f32_16x16x32_bf16(a[mi], bb[ni], acc[mi][ni], 0, 0, 0);
  }

  // C frag: col(j) = l16, rows r = 4*hi + reg  ->  PT[j][r] gets contiguous 8B per lane
#pragma unroll
  for (int mi = 0; mi < 4; ++mi) {
#pragma unroll
    for (int ni = 0; ni < 4; ++ni) {
      int j = ncol0 + ni * 16 + l16;
      int rb = mrow0 + mi * 16 + 4 * hi;
      bf16x4 pk;
#pragma unroll
      for (int r = 0; r < 4; ++r) pk[r] = (__bf16)acc[mi][ni][r];
      *reinterpret_cast<u16x4*>(PT + j * NN + rb) = __builtin_bit_cast(u16x4, pk);
    }
  }
}

// ---------------- pass 2: out = H P  (P^T rows are k-contiguous) ----------------
__global__ __launch_bounds__(256, 3) void dct_pass2(
    const int* __restrict__ steps, float* __restrict__ out) {
  int bid = blockIdx.x;
  int task = (bid & 7) * 192 + (bid >> 3);
  int img = task >> 2;
  int quad = task & 3;
  int s = steps[img / 3];

  const unsigned short* H = &g_H[s][0][0];
  const unsigned short* PT = g_PT + (size_t)img * (NN * NN);
  float* O = out + (size_t)img * (NN * NN);

  int tid = (int)threadIdx.x;
  int lane = tid & 63;
  int w = tid >> 6;
  int l16 = lane & 15;
  int hi = lane >> 4;
  int mrow0 = (quad >> 1) * 128 + (w >> 1) * 64;   // out row band (i = H row)
  int ncol0 = (quad & 1) * 128 + (w & 1) * 64;     // out col band (j = PT row)

  f32x4 acc[4][4];
#pragma unroll
  for (int mi = 0; mi < 4; ++mi)
#pragma unroll
    for (int ni = 0; ni < 4; ++ni)
      acc[mi][ni] = (f32x4){0.f, 0.f, 0.f, 0.f};

#pragma unroll 2
  for (int kk = 0; kk < 8; ++kk) {
    int k0 = kk * 32;
    bf16x8 a[4], bb[4];
#pragma unroll
    for (int mi = 0; mi < 4; ++mi) {
      int irow = mrow0 + mi * 16 + l16;
      u16x8 g = *reinterpret_cast<const u16x8*>(H + irow * NN + k0 + hi * 8);
      a[mi] = __builtin_bit_cast(bf16x8, g);
    }
#pragma unroll
    for (int ni = 0; ni < 4; ++ni) {
      int jrow = ncol0 + ni * 16 + l16;
      u16x8 z = *reinterpret_cast<const u16x8*>(PT + jrow * NN + k0 + hi * 8);
      bb[ni] = __builtin_bit_cast(bf16x8, z);
    }
#pragma unroll
    for (int mi = 0; mi < 4; ++mi)
#pragma unroll
      for (int ni = 0; ni < 4; ++ni)
        acc[mi][ni] = __builtin_amdgcn_mfma_f32_16x16x32_bf16(a[mi], bb[ni], acc[mi][ni], 0, 0, 0);
  }

  // C frag: col = j = l16, row = i = 4*hi + reg; fp32 stores (quarter-wave = 64B contiguous)
#pragma unroll
  for (int mi = 0; mi < 4; ++mi) {
#pragma unroll
    for (int ni = 0; ni < 4; ++ni) {
      int ibase = mrow0 + mi * 16 + 4 * hi;
      int jg = ncol0 + ni * 16 + l16;
#pragma unroll
      for (int r = 0; r < 4; ++r)
        O[(ibase + r) * NN + jg] = acc[mi][ni][r];
    }
  }
}

extern "C" void kernel_launch(void* const* d_in, const int* in_sizes, int n_in,
                              void* d_out, int out_size, void* d_ws, size_t ws_size,
                              hipStream_t stream) {
  (void)in_sizes; (void)n_in; (void)out_size; (void)d_ws; (void)ws_size;
  const float* x = (const float*)d_in[0];
  const float* sigmas = (const float*)d_in[1];
  const int* steps = (const int*)d_in[2];
  float* out = (float*)d_out;

  compute_U<<<dim3(NSTEP * 8), dim3(64), 0, stream>>>(sigmas);
  compute_H<<<dim3(NSTEP * NN), dim3(NN), 0, stream>>>(sigmas);
  dct_pass1<<<dim3(NIMG * 4), dim3(256), 0, stream>>>(x, steps);
  dct_pass2<<<dim3(NIMG * 4), dim3(256), 0, stream>>>(steps, out);
}